// Round 14
// baseline (2522.060 us; speedup 1.0000x reference)
//
#include <hip/hip_runtime.h>
#include <cstdio>

typedef __attribute__((ext_vector_type(8))) short short8;
typedef __attribute__((ext_vector_type(4))) float f32x4;
typedef unsigned long long u64;

#define MFMA16(a,b,c) __builtin_amdgcn_mfma_f32_16x16x32_bf16((a),(b),(c),0,0,0)
#define LOAD_SYS(p)    __hip_atomic_load((p), __ATOMIC_RELAXED, __HIP_MEMORY_SCOPE_SYSTEM)
#define STORE_SYS(p,v) __hip_atomic_store((p), (v), __ATOMIC_RELAXED, __HIP_MEMORY_SCOPE_SYSTEM)

typedef __attribute__((address_space(1))) unsigned AS1U;
typedef __attribute__((address_space(3))) unsigned AS3U;

// workspace layout (bytes). 32 row-groups of 16 rows; tiles are 16KB.
constexpr size_t CNT_OFF = 0;                            // 32 groups * 128B flag lines
constexpr size_t HB_OFF  = 8192;                         // 2 * 32 * 16KB = 1MB
constexpr size_t PK1_OFF = HB_OFF + 1048576;             // Wh1 pack, 2MB
constexpr size_t PK2_OFF = PK1_OFF + 2097152;            // Wh2 pack, 2MB
constexpr size_t PKX_OFF = PK2_OFF + 2097152;            // Wx2 pack, 2MB
constexpr size_t SEQ_OFF = PKX_OFF + 2097152;            // seq1: 32 * 200 * 16KB (~100MB)
constexpr size_t WS_NEED = SEQ_OFF + 32ul * 200 * 16384; // ~112.2 MB

__device__ __forceinline__ short f2bf(float f) {
  union { float f; unsigned u; } v; v.f = f;
  unsigned r = v.u + 0x7fffu + ((v.u >> 16) & 1u);
  return (short)(r >> 16);
}
__device__ __forceinline__ float bf2f(short s) {
  union { float f; unsigned u; } v; v.u = ((unsigned)(unsigned short)s) << 16;
  return v.f;
}
__device__ __forceinline__ float sigm(float x)   { return 1.f / (1.f + __expf(-x)); }
__device__ __forceinline__ float tanh_f(float x) { return 1.f - 2.f / (1.f + __expf(2.f * x)); }

// Pack W[512][2048] fp32 (K x N) into MFMA B-fragment order:
// frag (nf,kf): lane l, elem e holds B[k = kf*32 + (l>>4)*8 + e][n = nf*16 + (l&15)]
__global__ void pack_w(const float* __restrict__ wh1, const float* __restrict__ wh2,
                       const float* __restrict__ wx2, unsigned char* __restrict__ ws)
{
  int tid = blockIdx.x * 256 + threadIdx.x;   // 3 * 65536 threads
  int m   = tid >> 16;
  int rem = tid & 65535;
  int k   = rem >> 7;     // 0..511
  int nf  = rem & 127;    // 0..127
  const float* W = (m == 0) ? wh1 : (m == 1) ? wh2 : wx2;
  short* dst = (short*)(ws + ((m == 0) ? PK1_OFF : (m == 1) ? PK2_OFF : PKX_OFF));
  int kf = k >> 5, sub = (k >> 3) & 3, e = k & 7;
  int base = ((nf * 16 + kf) * 64 + sub * 16) * 8 + e;
  const float* src = W + (size_t)k * 2048 + nf * 16;
#pragma unroll
  for (int c = 0; c < 16; ++c) dst[base + c * 8] = f2bf(src[c]);
}

// stage one 16KB tile LLC->LDS (4 glds per wave, linear both sides)
__device__ __forceinline__ void stage16k(const char* g, char* l, int w, int lane) {
#pragma unroll
  for (int i = 0; i < 4; ++i)
    __builtin_amdgcn_global_load_lds(
        (const AS1U*)(g + (w * 4 + i) * 1024 + lane * 16),
        (AS3U*)(l + (w * 4 + i) * 1024), 16, 0, 17 /* sc0|sc1 */);
}

#define LGKM_BAR() do { \
  asm volatile("s_waitcnt lgkmcnt(0)" ::: "memory"); \
  __builtin_amdgcn_s_barrier(); \
  __builtin_amdgcn_sched_barrier(0); } while (0)

// MFMA half of a superstep: entry-drain + barrier, then all matrix work into regs.
__device__ __forceinline__ void phase_mfma(
    int s, int lane, int w,
    const short8* tA, const short8* tB,
    const short8 (&wh1f)[2][16], const short8 (&wh2f)[2][16],
    const short8 (&wxhi)[2][8], const short8 (&bwx)[4][2][8][64],
    f32x4 (&a1)[2], f32x4 (&a2)[2])
{
  asm volatile("s_waitcnt vmcnt(0)" ::: "memory");
  __builtin_amdgcn_sched_barrier(0);
  __builtin_amdgcn_s_barrier();
  __builtin_amdgcn_sched_barrier(0);

#pragma unroll
  for (int Gl = 0; Gl < 2; ++Gl) { f32x4 z = {0.f,0.f,0.f,0.f}; a1[Gl] = z; a2[Gl] = z; }

  if (s >= 1 && s <= 200) {
#pragma unroll
    for (int kf = 0; kf < 16; ++kf) {
      short8 a = tA[kf * 64 + lane];
#pragma unroll
      for (int Gl = 0; Gl < 2; ++Gl) {
        if (s < 200) a1[Gl] = MFMA16(a, wh1f[Gl][kf], a1[Gl]);
        short8 bxf = (kf < 8) ? bwx[w][Gl][kf][lane] : wxhi[Gl][kf - 8];
        a2[Gl] = MFMA16(a, bxf, a2[Gl]);
      }
    }
  }
  if (s >= 2 && s <= 200) {
#pragma unroll
    for (int kf = 0; kf < 16; ++kf) {
      short8 b = tB[kf * 64 + lane];
#pragma unroll
      for (int Gl = 0; Gl < 2; ++Gl)
        a2[Gl] = MFMA16(b, wh2f[Gl][kf], a2[Gl]);
    }
  }
}

// Tail half: zl scatter, gates, ht pack, stores, drain, flag post.
// The trailing __syncthreads also drains any stage issued just before this call.
__device__ __forceinline__ void phase_tail(
    int s, int tid, int lane, int w, int g0, int cf,
    f32x4 (&a1)[2], f32x4 (&a2)[2],
    float (&zl1)[16][132], float (&zl2)[16][132],
    unsigned short (&ht1)[16][36], unsigned short (&ht2)[16][36],
    const float* xg, const float (&wx1v)[4], const float (&b1v)[4], const float (&b2v)[4],
    float (&c1)[2], float (&c2)[2],
    u64* seqG, u64* hbG0, u64* hbG1,
    int pr, int pq, int bq, unsigned* fl, int wj)
{
  // scatter pre-activations
  {
    int orow = (lane >> 4) * 4, oc = cf * 16 + (lane & 15);
#pragma unroll
    for (int Gl = 0; Gl < 2; ++Gl) {
      int cc = (g0 + Gl) * 32 + oc;
#pragma unroll
      for (int r4 = 0; r4 < 4; ++r4) {
        if (s >= 0 && s < 200)  zl1[orow + r4][cc] = a1[Gl][r4];
        if (s >= 1 && s <= 200) zl2[orow + r4][cc] = a2[Gl][r4];
      }
    }
  }
  LGKM_BAR();   // zl ready

  // gates: thread owns hcol, rows rq*2, rq*2+1
  {
    int hcol = tid & 31, rq = tid >> 5;
#pragma unroll
    for (int i = 0; i < 2; ++i) {
      int row = rq * 2 + i;
      if (s >= 0 && s < 200) {
        float x  = xg[row * 200 + s];
        float z0 = zl1[row][hcol]       + fmaf(x, wx1v[0], b1v[0]);
        float z1 = zl1[row][32 + hcol]  + fmaf(x, wx1v[1], b1v[1]);
        float z2 = zl1[row][64 + hcol]  + fmaf(x, wx1v[2], b1v[2]);
        float z3 = zl1[row][96 + hcol]  + fmaf(x, wx1v[3], b1v[3]);
        float cv = sigm(z1) * c1[i] + sigm(z0) * tanh_f(z2);
        c1[i] = cv;
        ht1[row][hcol] = (unsigned short)f2bf(sigm(z3) * tanh_f(cv));
      }
      if (s >= 1 && s <= 200) {
        float z0 = zl2[row][hcol]       + b2v[0];
        float z1 = zl2[row][32 + hcol]  + b2v[1];
        float z2 = zl2[row][64 + hcol]  + b2v[2];
        float z3 = zl2[row][96 + hcol]  + b2v[3];
        float cv = sigm(z1) * c2[i] + sigm(z0) * tanh_f(z2);
        c2[i] = cv;
        ht2[row][hcol] = (unsigned short)f2bf(sigm(z3) * tanh_f(cv));
      }
    }
  }
  LGKM_BAR();   // ht ready

  if (tid < 128) {
    if (s >= 0 && s < 200)
      STORE_SYS(seqG + (size_t)s * 2048 + bq, *(const u64*)&ht1[pr][pq * 4]);
    if (s >= 1 && s <= 200)
      STORE_SYS(((((s + 1) & 1) ? hbG1 : hbG0) + bq), *(const u64*)&ht2[pr][pq * 4]);
  }
  __syncthreads();   // drains vmcnt(0): stores acked (and pending stage loads done)
  if (tid == 0 && s >= 0 && s <= 200)
    STORE_SYS(&fl[wj], (unsigned)(s + 1));
}

// poll: all 16 WGs of a group posted >= r (no RMW)
__device__ __forceinline__ void poll_group(const unsigned* fl, unsigned r, int tid) {
  if (tid < 64) {
    const unsigned* fp = &fl[tid & 15];
    while (1) {
      unsigned v = LOAD_SYS((unsigned*)fp);
      if (__all((int)(v >= r))) break;
      __builtin_amdgcn_s_sleep(1);
    }
    asm volatile("" ::: "memory");
  }
  __syncthreads();
}

// 256 WGs; WG (p, wj) serves groups A=2p, B=2p+1; owns h-cols [wj*32, wj*32+32).
// Round r: [mfmaB(r-1) | pollA(r) | stageA(r) | tailB->postB(r)
//           | mfmaA(r) | pollB(r) | stageB(r) | tailA->postA(r+1)]
// Stage RTs hide under the opposite group's tail; polls have >=1 mfma-phase of slack.
__global__ __launch_bounds__(256, 1) void lstm_main(
    const float* __restrict__ inp, const float* __restrict__ Wx1,
    const float* __restrict__ b1,  const float* __restrict__ b2,
    const float* __restrict__ Wfc, const float* __restrict__ bfc,
    unsigned char* __restrict__ ws, float* __restrict__ out)
{
  __shared__ short8 ldsAA[1024], ldsBA[1024];   // group A tiles (seq, hb), 32KB
  __shared__ short8 ldsAB[1024], ldsBB[1024];   // group B tiles, 32KB
  __shared__ short8 bwx[4][2][8][64];           // Wx2 kf<8 per wave, 64KB
  __shared__ float  zl1[16][132], zl2[16][132]; // pre-act exchange, 16.5KB
  __shared__ unsigned short ht1[16][36], ht2[16][36];
  __shared__ float  red[256];

  const int tid  = threadIdx.x;
  const int blk  = blockIdx.x;
  const int p    = blk >> 4;     // pair index 0..15
  const int wj   = blk & 15;     // h-col block
  const int grA  = 2 * p, grB = 2 * p + 1;
  const int w    = tid >> 6;
  const int lane = tid & 63;
  const int g0   = (w >> 1) << 1;
  const int cf   = w & 1;

  unsigned* flA = (unsigned*)(ws + CNT_OFF) + grA * 32;   // 128B lines
  unsigned* flB = (unsigned*)(ws + CNT_OFF) + grB * 32;
  u64* hbA0 = (u64*)(ws + HB_OFF + (size_t)(0 * 32 + grA) * 16384);
  u64* hbA1 = (u64*)(ws + HB_OFF + (size_t)(1 * 32 + grA) * 16384);
  u64* hbB0 = (u64*)(ws + HB_OFF + (size_t)(0 * 32 + grB) * 16384);
  u64* hbB1 = (u64*)(ws + HB_OFF + (size_t)(1 * 32 + grB) * 16384);
  const short8* pk1 = (const short8*)(ws + PK1_OFF);
  const short8* pk2 = (const short8*)(ws + PK2_OFF);
  const short8* pkx = (const short8*)(ws + PKX_OFF);
  u64* seqA = (u64*)(ws + SEQ_OFF + (size_t)grA * 200 * 16384);
  u64* seqB = (u64*)(ws + SEQ_OFF + (size_t)grB * 200 * 16384);

  // B-fragments: Wh1, Wh2 in VGPRs; Wx2 kf<8 -> LDS, kf>=8 -> VGPRs
  short8 wh1f[2][16], wh2f[2][16], wxhi[2][8];
#pragma unroll
  for (int Gl = 0; Gl < 2; ++Gl) {
    int nf = (g0 + Gl) * 32 + wj * 2 + cf;
#pragma unroll
    for (int kf = 0; kf < 16; ++kf) {
      wh1f[Gl][kf] = pk1[(nf * 16 + kf) * 64 + lane];
      wh2f[Gl][kf] = pk2[(nf * 16 + kf) * 64 + lane];
    }
#pragma unroll
    for (int kf = 0; kf < 8; ++kf)
      bwx[w][Gl][kf][lane] = pkx[(nf * 16 + kf) * 64 + lane];
#pragma unroll
    for (int kf = 8; kf < 16; ++kf)
      wxhi[Gl][kf - 8] = pkx[(nf * 16 + kf) * 64 + lane];
  }

  // gate constants for this thread's z-column
  const int hcol = tid & 31;
  const int jcol = wj * 32 + hcol;
  float wx1v[4], b1v[4], b2v[4];
#pragma unroll
  for (int G = 0; G < 4; ++G) {
    wx1v[G] = Wx1[G * 512 + jcol];
    b1v[G]  = b1[G * 512 + jcol];
    b2v[G]  = b2[G * 512 + jcol];
  }
  const float* xgA = inp + (size_t)(grA * 16) * 200;
  const float* xgB = inp + (size_t)(grB * 16) * 200;

  // pack-thread mapping (tid<128): row pr, 4 cols at pc0
  const int pr = (tid & 127) >> 3, pq = tid & 7;
  const int pc0 = wj * 32 + pq * 4;
  const int bq = (((pc0 >> 5) * 64 + ((pc0 >> 3) & 3) * 16 + pr) * 8 + (pc0 & 7)) >> 2;

  float cA1[2] = {0.f, 0.f}, cA2[2] = {0.f, 0.f};
  float cB1[2] = {0.f, 0.f}, cB2[2] = {0.f, 0.f};
  f32x4 aA1[2], aA2[2], aB1[2], aB2[2];

  __syncthreads();   // bwx staged

#pragma unroll 1
  for (int r = 0; r <= 201; ++r) {
    // ---- 1: MFMA half of B step r-1 (tiles staged at step 7 of round r-1) ----
    phase_mfma(r - 1, lane, w, ldsAB, ldsBB, wh1f, wh2f, wxhi, bwx, aB1, aB2);

    // ---- 2: poll A (slack: tailA of prev round + mfmaB) ----
    if (r >= 1 && r <= 200) poll_group(flA, (unsigned)r, tid);

    // ---- 3: issue A-stage (RT hides under tailB) ----
    if (r >= 1 && r <= 200)
      stage16k((const char*)seqA + (size_t)(r - 1) * 16384, (char*)ldsAA, w, lane);
    if (r >= 2 && r <= 200)
      stage16k((const char*)((r & 1) ? hbA1 : hbA0), (char*)ldsBA, w, lane);

    // ---- 4: tail of B step r-1 -> posts flB = r ----
    phase_tail(r - 1, tid, lane, w, g0, cf, aB1, aB2, zl1, zl2, ht1, ht2,
               xgB, wx1v, b1v, b2v, cB1, cB2, seqB, hbB0, hbB1, pr, pq, bq, flB, wj);

    // ---- 5: MFMA half of A step r (stage drained at step 4's barrier) ----
    phase_mfma(r, lane, w, ldsAA, ldsBA, wh1f, wh2f, wxhi, bwx, aA1, aA2);

    // ---- 6: poll B (slack: mfmaA) ----
    if (r >= 1 && r <= 200) poll_group(flB, (unsigned)r, tid);

    // ---- 7: issue B-stage (RT hides under tailA) ----
    if (r >= 1 && r <= 200)
      stage16k((const char*)seqB + (size_t)(r - 1) * 16384, (char*)ldsAB, w, lane);
    if (r >= 2 && r <= 200)
      stage16k((const char*)((r & 1) ? hbB1 : hbB0), (char*)ldsBB, w, lane);

    // ---- 8: tail of A step r -> posts flA = r+1 ----
    phase_tail(r, tid, lane, w, g0, cf, aA1, aA2, zl1, zl2, ht1, ht2,
               xgA, wx1v, b1v, b2v, cA1, cA2, seqA, hbA0, hbA1, pr, pq, bq, flA, wj);
  }

  // ---- final FC: logits = h2_199 @ Wfc + bfc (hb1 of each group) ----
  if (wj == 0) {
    if (tid < 64) {
      const unsigned* fa = &flA[tid & 15];
      while (1) {
        unsigned v = LOAD_SYS((unsigned*)fa);
        if (__all((int)(v >= 201u))) break;
        __builtin_amdgcn_s_sleep(1);
      }
      const unsigned* fb = &flB[tid & 15];
      while (1) {
        unsigned v = LOAD_SYS((unsigned*)fb);
        if (__all((int)(v >= 201u))) break;
        __builtin_amdgcn_s_sleep(1);
      }
      asm volatile("" ::: "memory");
    }
    __syncthreads();

    int r2 = tid >> 3, q = tid & 7;
    int row = r2 & 15;
    const u64* h2 = (r2 < 16) ? hbA1 : hbB1;
    float sum = 0.f;
#pragma unroll
    for (int c = 0; c < 8; ++c) {
      int k0 = q * 64 + c * 8;
      int bq2 = ((k0 >> 5) * 64 + ((k0 >> 3) & 3) * 16 + row) * 2;
      union { u64 u[2]; unsigned short ss[8]; } cv;
      cv.u[0] = LOAD_SYS((u64*)h2 + bq2);
      cv.u[1] = LOAD_SYS((u64*)h2 + bq2 + 1);
#pragma unroll
      for (int e = 0; e < 8; ++e)
        sum = fmaf(bf2f((short)cv.ss[e]), Wfc[k0 + e], sum);
    }
    red[tid] = sum;
    __syncthreads();
    if (q == 0) {
      float o = bfc[0];
#pragma unroll
      for (int j = 0; j < 8; ++j) o += red[r2 * 8 + j];
      int gr = (r2 < 16) ? grA : grB;
      out[gr * 16 + row] = o;
    }
  }
}

extern "C" void kernel_launch(void* const* d_in, const int* in_sizes, int n_in,
                              void* d_out, int out_size, void* d_ws, size_t ws_size,
                              hipStream_t stream)
{
  if (ws_size < WS_NEED) {
    fprintf(stderr, "kernel_launch: ws_size %zu < needed %zu\n", ws_size, WS_NEED);
    return;
  }
  const float* inp = (const float*)d_in[0];
  const float* Wx1 = (const float*)d_in[1];
  const float* Wh1 = (const float*)d_in[2];
  const float* b1  = (const float*)d_in[3];
  const float* Wx2 = (const float*)d_in[4];
  const float* Wh2 = (const float*)d_in[5];
  const float* b2  = (const float*)d_in[6];
  const float* Wfc = (const float*)d_in[7];
  const float* bfc = (const float*)d_in[8];
  unsigned char* ws = (unsigned char*)d_ws;

  hipMemsetAsync(ws, 0, 8192, stream);                        // flags
  pack_w<<<768, 256, 0, stream>>>(Wh1, Wh2, Wx2, ws);
  lstm_main<<<256, 256, 0, stream>>>(inp, Wx1, b1, b2, Wfc, bfc, ws, (float*)d_out);
}

// Round 15
// 1734.863 us; speedup vs baseline: 1.4538x; 1.4538x over previous
//
#include <hip/hip_runtime.h>
#include <cstdio>

typedef __attribute__((ext_vector_type(8))) short short8;
typedef __attribute__((ext_vector_type(4))) float f32x4;
typedef unsigned long long u64;

#define MFMA16(a,b,c) __builtin_amdgcn_mfma_f32_16x16x32_bf16((a),(b),(c),0,0,0)
#define LOAD_SYS(p)    __hip_atomic_load((p), __ATOMIC_RELAXED, __HIP_MEMORY_SCOPE_SYSTEM)
#define STORE_SYS(p,v) __hip_atomic_store((p), (v), __ATOMIC_RELAXED, __HIP_MEMORY_SCOPE_SYSTEM)

typedef __attribute__((address_space(1))) unsigned AS1U;
typedef __attribute__((address_space(3))) unsigned AS3U;

// workspace layout (bytes). 16 row-groups of 32 rows; tiles are 32KB. (R11 layout)
constexpr size_t CNT_OFF = 0;                            // 16 groups * 128B flag lines
constexpr size_t HB_OFF  = 8192;                         // 2 * 16 * 32KB = 1MB
constexpr size_t PK1_OFF = HB_OFF + 1048576;             // Wh1 pack, 2MB
constexpr size_t PK2_OFF = PK1_OFF + 2097152;            // Wh2 pack, 2MB
constexpr size_t PKX_OFF = PK2_OFF + 2097152;            // Wx2 pack, 2MB
constexpr size_t SEQ_OFF = PKX_OFF + 2097152;            // seq1: 16 * 200 * 32KB (~105MB)
constexpr size_t WS_NEED = SEQ_OFF + 16ul * 200 * 32768; // ~110 MB

__device__ __forceinline__ short f2bf(float f) {
  union { float f; unsigned u; } v; v.f = f;
  unsigned r = v.u + 0x7fffu + ((v.u >> 16) & 1u);
  return (short)(r >> 16);
}
__device__ __forceinline__ float bf2f(short s) {
  union { float f; unsigned u; } v; v.u = ((unsigned)(unsigned short)s) << 16;
  return v.f;
}
__device__ __forceinline__ float sigm(float x)   { return 1.f / (1.f + __expf(-x)); }
__device__ __forceinline__ float tanh_f(float x) { return 1.f - 2.f / (1.f + __expf(2.f * x)); }

// Pack W[512][2048] fp32 (K x N) into MFMA B-fragment order:
// frag (nf,kf): lane l, elem e holds B[k = kf*32 + (l>>4)*8 + e][n = nf*16 + (l&15)]
__global__ void pack_w(const float* __restrict__ wh1, const float* __restrict__ wh2,
                       const float* __restrict__ wx2, unsigned char* __restrict__ ws)
{
  int tid = blockIdx.x * 256 + threadIdx.x;   // 3 * 65536 threads
  int m   = tid >> 16;
  int rem = tid & 65535;
  int k   = rem >> 7;     // 0..511
  int nf  = rem & 127;    // 0..127
  const float* W = (m == 0) ? wh1 : (m == 1) ? wh2 : wx2;
  short* dst = (short*)(ws + ((m == 0) ? PK1_OFF : (m == 1) ? PK2_OFF : PKX_OFF));
  int kf = k >> 5, sub = (k >> 3) & 3, e = k & 7;
  int base = ((nf * 16 + kf) * 64 + sub * 16) * 8 + e;
  const float* src = W + (size_t)k * 2048 + nf * 16;
#pragma unroll
  for (int c = 0; c < 16; ++c) dst[base + c * 8] = f2bf(src[c]);
}

// stage one 32KB tile -> LDS (8 glds per wave, linear both sides)
__device__ __forceinline__ void stage32k_cached(const char* g, char* l, int w, int lane) {
#pragma unroll
  for (int i = 0; i < 8; ++i)
    __builtin_amdgcn_global_load_lds(
        (const AS1U*)(g + (w * 8 + i) * 1024 + lane * 16),
        (AS3U*)(l + (w * 8 + i) * 1024), 16, 0, 0 /* cached: write-once src */);
}
__device__ __forceinline__ void stage32k_llc(const char* g, char* l, int w, int lane) {
#pragma unroll
  for (int i = 0; i < 8; ++i)
    __builtin_amdgcn_global_load_lds(
        (const AS1U*)(g + (w * 8 + i) * 1024 + lane * 16),
        (AS3U*)(l + (w * 8 + i) * 1024), 16, 0, 17 /* sc0|sc1: rewritten src */);
}

#define LGKM_BAR() do { \
  asm volatile("s_waitcnt lgkmcnt(0)" ::: "memory"); \
  __builtin_amdgcn_s_barrier(); \
  __builtin_amdgcn_sched_barrier(0); } while (0)

// 16 groups x 32 rows; 16 WGs/group, each owns h-cols [wj*32, wj*32+32) (x4 gates).
// Superstep s: L1 step s + L2 step s-1 (diagonal fusion). 5 barriers/superstep.
__global__ __launch_bounds__(256, 1) void lstm_main(
    const float* __restrict__ inp, const float* __restrict__ Wx1,
    const float* __restrict__ b1,  const float* __restrict__ b2,
    const float* __restrict__ Wfc, const float* __restrict__ bfc,
    unsigned char* __restrict__ ws, float* __restrict__ out)
{
  __shared__ short8 ldsA[2048];              // seq tile (h1_{s-1}), 32KB
  __shared__ short8 ldsB[2048];              // hb tile (h2_{s-2}), 32KB
  __shared__ short8 bwx[4][2][8][64];        // Wx2 kf<8 per wave, 64KB
  __shared__ float  zl1[32][132];            // L1 pre-acts, f32, 16.5KB
  __shared__ unsigned short zl2[32][132];    // L2 pre-acts, bf16, 8.25KB
  __shared__ unsigned short ht1[32][36];     // h1 transpose staging, 2.25KB
  __shared__ unsigned short ht2[32][36];     // h2 transpose staging, 2.25KB
  __shared__ float  red[256];

  const int tid  = threadIdx.x;
  const int blk  = blockIdx.x;
  const int gr   = blk & 15;    // row-group (32 rows); all 16 WGs land on XCD gr%8
  const int wj   = blk >> 4;    // 0..15: h-cols [wj*32, wj*32+32)
  const int w    = tid >> 6;
  const int lane = tid & 63;
  const int g0   = (w >> 1) << 1;   // this wave's gate pair
  const int cf   = w & 1;           // col-frag within the 32 h-cols

  unsigned* fl = (unsigned*)(ws + CNT_OFF) + gr * 32;   // 32 words: [wj]=wave0, [16+wj]=wave1
  u64* hbU0 = (u64*)(ws + HB_OFF + (size_t)(0 * 16 + gr) * 32768);
  u64* hbU1 = (u64*)(ws + HB_OFF + (size_t)(1 * 16 + gr) * 32768);
  const short8* pk1 = (const short8*)(ws + PK1_OFF);
  const short8* pk2 = (const short8*)(ws + PK2_OFF);
  const short8* pkx = (const short8*)(ws + PKX_OFF);
  u64* seqU = (u64*)(ws + SEQ_OFF + (size_t)gr * 200 * 32768);

  // B-fragments: Wh1, Wh2 in VGPRs; Wx2 kf<8 -> LDS, kf>=8 -> VGPRs  (R11-proven split)
  short8 wh1f[2][16], wh2f[2][16], wxhi[2][8];
#pragma unroll
  for (int Gl = 0; Gl < 2; ++Gl) {
    int nf = (g0 + Gl) * 32 + wj * 2 + cf;
#pragma unroll
    for (int kf = 0; kf < 16; ++kf) {
      wh1f[Gl][kf] = pk1[(nf * 16 + kf) * 64 + lane];
      wh2f[Gl][kf] = pk2[(nf * 16 + kf) * 64 + lane];
    }
#pragma unroll
    for (int kf = 0; kf < 8; ++kf)
      bwx[w][Gl][kf][lane] = pkx[(nf * 16 + kf) * 64 + lane];
#pragma unroll
    for (int kf = 8; kf < 16; ++kf)
      wxhi[Gl][kf - 8] = pkx[(nf * 16 + kf) * 64 + lane];
  }

  // gate constants: thread owns z-column jcol, rows rq*4..rq*4+3
  const int hcol = tid & 31, rq = tid >> 5;
  const int jcol = wj * 32 + hcol;
  float wx1v[4], b1v[4], b2v[4];
#pragma unroll
  for (int G = 0; G < 4; ++G) {
    wx1v[G] = Wx1[G * 512 + jcol];
    b1v[G]  = b1[G * 512 + jcol];
    b2v[G]  = b2[G * 512 + jcol];
  }
  const float* xptr = inp + (size_t)(gr * 32 + rq * 4) * 200;

  // store mapping (tid<128): row spr = tid>>2, col-quads spqa=(tid&3)*2, spqb=spqa+1
  const int spr = tid >> 2, spqa = (tid & 3) * 2, spqb = spqa + 1;
  auto bqof = [&](int pq) {
    int pc0 = wj * 32 + pq * 4;
    return ((((pc0 >> 5) * 2 + (spr >> 4)) * 64 + ((pc0 >> 3) & 3) * 16 + (spr & 15)) * 8
            + (pc0 & 7)) >> 2;
  };
  const int bqa = bqof(spqa), bqb = bqof(spqb);

  float cst1[4] = {0.f, 0.f, 0.f, 0.f};   // layer-1 c state
  float cst2[4] = {0.f, 0.f, 0.f, 0.f};   // layer-2 c state

  __syncthreads();   // bwx staged

#pragma unroll 1
  for (int s = 0; s <= 200; ++s) {
    // ---- prefetch L1 x values (independent of flags) ----
    float xv[4];
    if (s < 200) {
#pragma unroll
      for (int i = 0; i < 4; ++i) xv[i] = xptr[i * 200 + s];
    }

    // ---- B1: poll (32 lanes, one flag word each) ----
    if (s > 0) {
      if (tid < 32) {
        const unsigned* fp = &fl[tid];
        while (1) {
          unsigned v = LOAD_SYS((unsigned*)fp);
          if (__all((int)(v >= (unsigned)s))) break;
          __builtin_amdgcn_s_sleep(1);
        }
        asm volatile("" ::: "memory");
      }
    }
    __syncthreads();

    // ---- stage: seq[s-1] cached (write-once, L2-local); hb LLC-fresh ----
    if (s >= 1)
      stage32k_cached((const char*)(seqU + (size_t)(s - 1) * 4096), (char*)ldsA, w, lane);
    if (s >= 2)
      stage32k_llc((const char*)((s & 1) ? hbU1 : hbU0), (char*)ldsB, w, lane);
    __builtin_amdgcn_sched_barrier(0);
    if (s >= 2) asm volatile("s_waitcnt vmcnt(8)" ::: "memory");   // ldsA done, ldsB in flight
    else        asm volatile("s_waitcnt vmcnt(0)" ::: "memory");
    __builtin_amdgcn_sched_barrier(0);
    __builtin_amdgcn_s_barrier();   // B2: ldsA ready
    __builtin_amdgcn_sched_barrier(0);

    f32x4 acc1[2][2], acc2[2][2];
#pragma unroll
    for (int Gl = 0; Gl < 2; ++Gl)
#pragma unroll
      for (int m = 0; m < 2; ++m) {
        f32x4 z = {0.f, 0.f, 0.f, 0.f}; acc1[Gl][m] = z; acc2[Gl][m] = z;
      }

    // ---- setA: L1 recurrent + L2 x-projection (both consume ldsA) ----
    if (s >= 1) {
#pragma unroll
      for (int m = 0; m < 2; ++m) {
#pragma unroll
        for (int kf = 0; kf < 16; ++kf) {
          short8 a = ldsA[(kf * 2 + m) * 64 + lane];
#pragma unroll
          for (int Gl = 0; Gl < 2; ++Gl) {
            if (s < 200) acc1[Gl][m] = MFMA16(a, wh1f[Gl][kf], acc1[Gl][m]);
            short8 bx = (kf < 8) ? bwx[w][Gl][kf][lane] : wxhi[Gl][kf - 8];
            acc2[Gl][m] = MFMA16(a, bx, acc2[Gl][m]);
          }
        }
      }
    }

    asm volatile("s_waitcnt vmcnt(0)" ::: "memory");
    __builtin_amdgcn_sched_barrier(0);
    __builtin_amdgcn_s_barrier();   // B3: ldsB ready
    __builtin_amdgcn_sched_barrier(0);

    // ---- setB: L2 recurrent from ldsB ----
    if (s >= 2) {
#pragma unroll
      for (int m = 0; m < 2; ++m) {
#pragma unroll
        for (int kf = 0; kf < 16; ++kf) {
          short8 b = ldsB[(kf * 2 + m) * 64 + lane];
#pragma unroll
          for (int Gl = 0; Gl < 2; ++Gl)
            acc2[Gl][m] = MFMA16(b, wh2f[Gl][kf], acc2[Gl][m]);
        }
      }
    }

    // ---- single scatter: zl1 (f32) + zl2 (bf16) ----
    {
      int orow = (lane >> 4) * 4, oc = cf * 16 + (lane & 15);
#pragma unroll
      for (int Gl = 0; Gl < 2; ++Gl) {
        int cc = (g0 + Gl) * 32 + oc;
#pragma unroll
        for (int m = 0; m < 2; ++m)
#pragma unroll
          for (int r4 = 0; r4 < 4; ++r4) {
            int row = m * 16 + orow + r4;
            if (s < 200)  zl1[row][cc] = acc1[Gl][m][r4];
            if (s >= 1)   zl2[row][cc] = (unsigned short)f2bf(acc2[Gl][m][r4]);
          }
      }
    }
    LGKM_BAR();   // B4: zl ready

    // ---- merged gates: L1 (step s) + L2 (step s-1) ----
#pragma unroll
    for (int i = 0; i < 4; ++i) {
      int row = rq * 4 + i;
      if (s < 200) {
        float z0 = zl1[row][hcol]      + fmaf(xv[i], wx1v[0], b1v[0]);
        float z1 = zl1[row][32 + hcol] + fmaf(xv[i], wx1v[1], b1v[1]);
        float z2 = zl1[row][64 + hcol] + fmaf(xv[i], wx1v[2], b1v[2]);
        float z3 = zl1[row][96 + hcol] + fmaf(xv[i], wx1v[3], b1v[3]);
        float cc = sigm(z1) * cst1[i] + sigm(z0) * tanh_f(z2);
        cst1[i] = cc;
        ht1[row][hcol] = (unsigned short)f2bf(sigm(z3) * tanh_f(cc));
      }
      if (s >= 1) {
        float z0 = bf2f((short)zl2[row][hcol])      + b2v[0];
        float z1 = bf2f((short)zl2[row][32 + hcol]) + b2v[1];
        float z2 = bf2f((short)zl2[row][64 + hcol]) + b2v[2];
        float z3 = bf2f((short)zl2[row][96 + hcol]) + b2v[3];
        float cc = sigm(z1) * cst2[i] + sigm(z0) * tanh_f(z2);
        cst2[i] = cc;
        ht2[row][hcol] = (unsigned short)f2bf(sigm(z3) * tanh_f(cc));
      }
    }
    LGKM_BAR();   // B5: ht ready

    // ---- stores by waves 0-1; per-wave drain + half-flag post (no extra barrier) ----
    if (tid < 128) {
      if (s < 200) {
        u64* d = seqU + (size_t)s * 4096;
        STORE_SYS(d + bqa, *(const u64*)&ht1[spr][spqa * 4]);
        STORE_SYS(d + bqb, *(const u64*)&ht1[spr][spqb * 4]);
      }
      if (s >= 1) {
        u64* d = ((s + 1) & 1) ? hbU1 : hbU0;
        STORE_SYS(d + bqa, *(const u64*)&ht2[spr][spqa * 4]);
        STORE_SYS(d + bqb, *(const u64*)&ht2[spr][spqb * 4]);
      }
      asm volatile("s_waitcnt vmcnt(0)" ::: "memory");
      if ((tid & 63) == 0)
        STORE_SYS(&fl[(tid >> 6) * 16 + wj], (unsigned)(s + 1));
    }
    // waves 2-3 run ahead to next poll; B1's syncthreads re-joins everyone
  }

  // ---- final FC: logits = h2_199 @ Wfc + bfc (s=200 wrote hbU1) ----
  if (wj == 0) {
    if (tid < 32) {
      const unsigned* fp = &fl[tid];
      while (1) {
        unsigned v = LOAD_SYS((unsigned*)fp);
        if (__all((int)(v >= 201u))) break;
        __builtin_amdgcn_s_sleep(1);
      }
      asm volatile("" ::: "memory");
    }
    __syncthreads();

    int r2 = tid >> 3, q = tid & 7;
    float sum = 0.f;
#pragma unroll
    for (int c = 0; c < 8; ++c) {
      int k0 = q * 64 + c * 8;
      int kf = k0 >> 5, sub = (k0 >> 3) & 3, m = r2 >> 4;
      int bq2 = ((kf * 2 + m) * 64 + sub * 16 + (r2 & 15)) * 2;
      union { u64 u[2]; unsigned short ss[8]; } cv;
      cv.u[0] = LOAD_SYS(hbU1 + bq2);
      cv.u[1] = LOAD_SYS(hbU1 + bq2 + 1);
#pragma unroll
      for (int e = 0; e < 8; ++e)
        sum = fmaf(bf2f((short)cv.ss[e]), Wfc[k0 + e], sum);
    }
    red[tid] = sum;
    __syncthreads();
    if (q == 0) {
      float o = bfc[0];
#pragma unroll
      for (int j = 0; j < 8; ++j) o += red[r2 * 8 + j];
      out[gr * 32 + r2] = o;
    }
  }
}

extern "C" void kernel_launch(void* const* d_in, const int* in_sizes, int n_in,
                              void* d_out, int out_size, void* d_ws, size_t ws_size,
                              hipStream_t stream)
{
  if (ws_size < WS_NEED) {
    fprintf(stderr, "kernel_launch: ws_size %zu < needed %zu\n", ws_size, WS_NEED);
    return;
  }
  const float* inp = (const float*)d_in[0];
  const float* Wx1 = (const float*)d_in[1];
  const float* Wh1 = (const float*)d_in[2];
  const float* b1  = (const float*)d_in[3];
  const float* Wx2 = (const float*)d_in[4];
  const float* Wh2 = (const float*)d_in[5];
  const float* b2  = (const float*)d_in[6];
  const float* Wfc = (const float*)d_in[7];
  const float* bfc = (const float*)d_in[8];
  unsigned char* ws = (unsigned char*)d_ws;

  hipMemsetAsync(ws, 0, 8192, stream);                        // flags
  pack_w<<<768, 256, 0, stream>>>(Wh1, Wh2, Wx2, ws);
  lstm_main<<<256, 256, 0, stream>>>(inp, Wx1, b1, b2, Wfc, bfc, ws, (float*)d_out);
}

// Round 16
// 1449.835 us; speedup vs baseline: 1.7395x; 1.1966x over previous
//
#include <hip/hip_runtime.h>
#include <cstdio>

typedef __attribute__((ext_vector_type(8))) short short8;
typedef __attribute__((ext_vector_type(4))) float f32x4;
typedef unsigned long long u64;

#define MFMA16(a,b,c) __builtin_amdgcn_mfma_f32_16x16x32_bf16((a),(b),(c),0,0,0)
#define LOAD_SYS(p)    __hip_atomic_load((p), __ATOMIC_RELAXED, __HIP_MEMORY_SCOPE_SYSTEM)
#define STORE_SYS(p,v) __hip_atomic_store((p), (v), __ATOMIC_RELAXED, __HIP_MEMORY_SCOPE_SYSTEM)

typedef __attribute__((address_space(1))) unsigned AS1U;
typedef __attribute__((address_space(3))) unsigned AS3U;

// workspace layout (bytes). 16 row-groups of 32 rows; tiles are 32KB.
constexpr size_t CNT_OFF = 0;                            // 16 groups * 32 flag words
constexpr size_t HB_OFF  = 8192;                         // 2 * 16 * 32KB = 1MB
constexpr size_t PK1_OFF = HB_OFF + 1048576;             // Wh1 pack, 2MB
constexpr size_t PK2_OFF = PK1_OFF + 2097152;            // Wh2 pack, 2MB
constexpr size_t PKX_OFF = PK2_OFF + 2097152;            // Wx2 pack, 2MB
constexpr size_t SEQ_OFF = PKX_OFF + 2097152;            // seq1: 16 * 200 * 32KB (~102MB)
constexpr size_t WS_NEED = SEQ_OFF + 16ul * 200 * 32768; // ~110 MB

__device__ __forceinline__ short f2bf(float f) {
  union { float f; unsigned u; } v; v.f = f;
  unsigned r = v.u + 0x7fffu + ((v.u >> 16) & 1u);
  return (short)(r >> 16);
}
__device__ __forceinline__ float bf2f(short s) {
  union { float f; unsigned u; } v; v.u = ((unsigned)(unsigned short)s) << 16;
  return v.f;
}
__device__ __forceinline__ float sigm(float x)   { return 1.f / (1.f + __expf(-x)); }
__device__ __forceinline__ float tanh_f(float x) { return 1.f - 2.f / (1.f + __expf(2.f * x)); }

// Pack W[512][2048] fp32 (K x N) into MFMA B-fragment order:
// frag (nf,kf): lane l, elem e holds B[k = kf*32 + (l>>4)*8 + e][n = nf*16 + (l&15)]
__global__ void pack_w(const float* __restrict__ wh1, const float* __restrict__ wh2,
                       const float* __restrict__ wx2, unsigned char* __restrict__ ws)
{
  int tid = blockIdx.x * 256 + threadIdx.x;   // 3 * 65536 threads
  int m   = tid >> 16;
  int rem = tid & 65535;
  int k   = rem >> 7;     // 0..511
  int nf  = rem & 127;    // 0..127
  const float* W = (m == 0) ? wh1 : (m == 1) ? wh2 : wx2;
  short* dst = (short*)(ws + ((m == 0) ? PK1_OFF : (m == 1) ? PK2_OFF : PKX_OFF));
  int kf = k >> 5, sub = (k >> 3) & 3, e = k & 7;
  int base = ((nf * 16 + kf) * 64 + sub * 16) * 8 + e;
  const float* src = W + (size_t)k * 2048 + nf * 16;
#pragma unroll
  for (int c = 0; c < 16; ++c) dst[base + c * 8] = f2bf(src[c]);
}

// 16 groups x 32 rows; 16 WGs/group, each owns h-cols [wj*32, wj*32+32) (x4 gates).
// Wave w: gates {2(w>>1), 2(w>>1)+1}, col-frag (w&1). A-tiles staged via global_load_lds.
__global__ __launch_bounds__(256, 1) void lstm_main(
    const float* __restrict__ inp, const float* __restrict__ Wx1,
    const float* __restrict__ b1,  const float* __restrict__ b2,
    const float* __restrict__ Wfc, const float* __restrict__ bfc,
    unsigned char* __restrict__ ws, float* __restrict__ out)
{
  __shared__ short8 ldsA[2048];              // seq tile, 32KB
  __shared__ short8 ldsB[2048];              // h2 tile, 32KB
  __shared__ short8 bwx[4][2][8][64];        // Wx2 kf<8 per wave, 64KB
  __shared__ float  zlds[32][132];           // pre-activation exchange, 16.5KB
  __shared__ unsigned short htile[32][36];   // h transpose staging, 2.25KB
  __shared__ float  red[256];

  const int tid  = threadIdx.x;
  const int blk  = blockIdx.x;
  const int gr   = blk & 15;    // row-group (32 rows)
  const int wj   = blk >> 4;    // 0..15: h-cols [wj*32, wj*32+32)
  const int w    = tid >> 6;
  const int lane = tid & 63;
  const int g0   = (w >> 1) << 1;   // this wave's gate pair
  const int cf   = w & 1;           // col-frag within the 32 h-cols

  unsigned* fl = (unsigned*)(ws + CNT_OFF) + gr * 32;   // 16 flags on one line
  short8* hb0p = (short8*)(ws + HB_OFF) + (size_t)(0 * 16 + gr) * 2048;
  short8* hb1p = (short8*)(ws + HB_OFF) + (size_t)(1 * 16 + gr) * 2048;
  const short8* pk1 = (const short8*)(ws + PK1_OFF);
  const short8* pk2 = (const short8*)(ws + PK2_OFF);
  const short8* pkx = (const short8*)(ws + PKX_OFF);
  short8* seq = (short8*)(ws + SEQ_OFF) + (size_t)gr * (200 * 2048);

  // B-fragments: Wh1, Wh2 fully in VGPRs; Wx2 kf<8 -> LDS, kf>=8 -> VGPRs
  short8 wh1f[2][16], wh2f[2][16], wxhi[2][8];
#pragma unroll
  for (int Gl = 0; Gl < 2; ++Gl) {
    int nf = (g0 + Gl) * 32 + wj * 2 + cf;
#pragma unroll
    for (int kf = 0; kf < 16; ++kf) {
      wh1f[Gl][kf] = pk1[(nf * 16 + kf) * 64 + lane];
      wh2f[Gl][kf] = pk2[(nf * 16 + kf) * 64 + lane];
    }
#pragma unroll
    for (int kf = 0; kf < 8; ++kf)
      bwx[w][Gl][kf][lane] = pkx[(nf * 16 + kf) * 64 + lane];
#pragma unroll
    for (int kf = 8; kf < 16; ++kf)
      wxhi[Gl][kf - 8] = pkx[(nf * 16 + kf) * 64 + lane];
  }

  // gate-thread mapping: hcol = tid&31, rows rq*4..+3
  const int hcol = tid & 31, rq = tid >> 5;
  const int jcol = wj * 32 + hcol;
  float wx1v[4], b1v[4], b2v[4];
#pragma unroll
  for (int G = 0; G < 4; ++G) {
    wx1v[G] = Wx1[G * 512 + jcol];
    b1v[G]  = b1[G * 512 + jcol];
    b2v[G]  = b2[G * 512 + jcol];
  }
  const float* xptr = inp + (size_t)(gr * 32 + rq * 4) * 200;

  // pack-thread mapping: row pr, 4 cols at pc0
  const int pr = tid >> 3, pq = tid & 7;
  const int pc0 = wj * 32 + pq * 4;
  const int bq = ((((pc0 >> 5) * 2 + (pr >> 4)) * 64 + ((pc0 >> 3) & 3) * 16 + (pr & 15)) * 8
                  + (pc0 & 7)) >> 2;   // u64 index into 32-row A-frag pack

  float cst1[4] = {0.f, 0.f, 0.f, 0.f};
  float cst2[4] = {0.f, 0.f, 0.f, 0.f};

  __syncthreads();   // bwx staged

#pragma unroll 1
  for (int s = 0; s <= 200; ++s) {
    float xv[4];
    if (s < 200) {
#pragma unroll
      for (int i = 0; i < 4; ++i) xv[i] = xptr[i * 200 + s];
    }

    if (s > 0) {
      if (tid < 64) {
        const unsigned* fp = &fl[tid & 15];
        while (1) {
          unsigned v = LOAD_SYS((unsigned*)fp);
          if (__all((int)(v >= (unsigned)s))) break;
          __builtin_amdgcn_s_sleep(1);
        }
        asm volatile("" ::: "memory");
      }
    }
    __syncthreads();   // (1) all waves gated; prior-step LDS reads complete

    // ---- merged async stage: seq[s-1] -> ldsA, h2_{s-2} -> ldsB (LLC-direct) ----
    if (s >= 1) {
      const char* gsrc = (const char*)(seq + (size_t)(s - 1) * 2048);
      char* ldst = (char*)ldsA;
#pragma unroll
      for (int i = 0; i < 8; ++i)
        __builtin_amdgcn_global_load_lds(
            (const AS1U*)(gsrc + (w * 8 + i) * 1024 + lane * 16),
            (AS3U*)(ldst + (w * 8 + i) * 1024), 16, 0, 17 /* sc0|sc1 */);
    }
    if (s >= 2) {
      const char* gsrc = (const char*)((s & 1) ? hb1p : hb0p);
      char* ldst = (char*)ldsB;
#pragma unroll
      for (int i = 0; i < 8; ++i)
        __builtin_amdgcn_global_load_lds(
            (const AS1U*)(gsrc + (w * 8 + i) * 1024 + lane * 16),
            (AS3U*)(ldst + (w * 8 + i) * 1024), 16, 0, 17);
    }
    __builtin_amdgcn_sched_barrier(0);
    if (s >= 2) asm volatile("s_waitcnt vmcnt(8)" ::: "memory");   // seq done, hb in flight
    else        asm volatile("s_waitcnt vmcnt(0)" ::: "memory");
    __builtin_amdgcn_sched_barrier(0);
    __builtin_amdgcn_s_barrier();   // (2) ldsA ready for all waves

    f32x4 acc1[2][2], acc2[2][2];
#pragma unroll
    for (int Gl = 0; Gl < 2; ++Gl)
#pragma unroll
      for (int m = 0; m < 2; ++m) {
        f32x4 z = {0.f, 0.f, 0.f, 0.f}; acc1[Gl][m] = z; acc2[Gl][m] = z;
      }

    // ---- L1 recurrent + L2 x-projection: both consume ldsA ----
    if (s >= 1) {
#pragma unroll
      for (int m = 0; m < 2; ++m) {
#pragma unroll
        for (int kf = 0; kf < 16; ++kf) {
          short8 a = ldsA[(kf * 2 + m) * 64 + lane];
#pragma unroll
          for (int Gl = 0; Gl < 2; ++Gl) {
            if (s < 200) acc1[Gl][m] = MFMA16(a, wh1f[Gl][kf], acc1[Gl][m]);
            short8 bx = (kf < 8) ? bwx[w][Gl][kf][lane] : wxhi[Gl][kf - 8];
            acc2[Gl][m] = MFMA16(a, bx, acc2[Gl][m]);
          }
        }
      }
    }

    // ---- L1 pre-acts -> zlds (s==0: zeros) ----
    if (s < 200) {
#pragma unroll
      for (int Gl = 0; Gl < 2; ++Gl)
#pragma unroll
        for (int m = 0; m < 2; ++m)
#pragma unroll
          for (int r = 0; r < 4; ++r)
            zlds[m * 16 + (lane >> 4) * 4 + r][(g0 + Gl) * 32 + cf * 16 + (lane & 15)]
                = acc1[Gl][m][r];
    }
    __syncthreads();   // (3) zlds(L1) ready; ldsB ready (vmcnt drained)

    // ---- L1 gates ----
    if (s < 200) {
#pragma unroll
      for (int i = 0; i < 4; ++i) {
        int row = rq * 4 + i;
        float zi = zlds[row][0 * 32 + hcol] + fmaf(xv[i], wx1v[0], b1v[0]);
        float zf = zlds[row][1 * 32 + hcol] + fmaf(xv[i], wx1v[1], b1v[1]);
        float zg = zlds[row][2 * 32 + hcol] + fmaf(xv[i], wx1v[2], b1v[2]);
        float zo = zlds[row][3 * 32 + hcol] + fmaf(xv[i], wx1v[3], b1v[3]);
        float cc = sigm(zf) * cst1[i] + sigm(zi) * tanh_f(zg);
        cst1[i] = cc;
        htile[row][hcol] = (unsigned short)f2bf(sigm(zo) * tanh_f(cc));
      }
    }

    // ---- L2 recurrent from ldsB ----
    if (s >= 2) {
#pragma unroll
      for (int m = 0; m < 2; ++m) {
#pragma unroll
        for (int kf = 0; kf < 16; ++kf) {
          short8 a = ldsB[(kf * 2 + m) * 64 + lane];
#pragma unroll
          for (int Gl = 0; Gl < 2; ++Gl)
            acc2[Gl][m] = MFMA16(a, wh2f[Gl][kf], acc2[Gl][m]);
        }
      }
    }
    __syncthreads();   // (4) htile(L1) ready; zlds free

    if (s < 200) {
      u64 hv = *(const u64*)&htile[pr][pq * 4];
      STORE_SYS((u64*)(seq + (size_t)s * 2048) + bq, hv);
    }

    // ---- L2 pre-acts -> zlds ----
    if (s >= 1) {
#pragma unroll
      for (int Gl = 0; Gl < 2; ++Gl)
#pragma unroll
        for (int m = 0; m < 2; ++m)
#pragma unroll
          for (int r = 0; r < 4; ++r)
            zlds[m * 16 + (lane >> 4) * 4 + r][(g0 + Gl) * 32 + cf * 16 + (lane & 15)]
                = acc2[Gl][m][r];
    }
    __syncthreads();   // (5) zlds(L2) ready; htile(L1) consumed

    // ---- L2 gates ----
    if (s >= 1) {
#pragma unroll
      for (int i = 0; i < 4; ++i) {
        int row = rq * 4 + i;
        float zi = zlds[row][0 * 32 + hcol] + b2v[0];
        float zf = zlds[row][1 * 32 + hcol] + b2v[1];
        float zg = zlds[row][2 * 32 + hcol] + b2v[2];
        float zo = zlds[row][3 * 32 + hcol] + b2v[3];
        float cc = sigm(zf) * cst2[i] + sigm(zi) * tanh_f(zg);
        cst2[i] = cc;
        htile[row][hcol] = (unsigned short)f2bf(sigm(zo) * tanh_f(cc));
      }
    }
    __syncthreads();   // (6) htile(L2) ready

    if (s >= 1) {
      u64 hv = *(const u64*)&htile[pr][pq * 4];
      short8* dst = (s & 1) ? hb0p : hb1p;   // hb[(s+1)&1]
      STORE_SYS((u64*)dst + bq, hv);
    }
    __syncthreads();   // (7) stores drained (vmcnt 0) before post
    if (tid == 0)
      STORE_SYS(&fl[wj], (unsigned)(s + 1));
  }

  // final FC: logits = h2_199 @ Wfc + bfc  (s=200 wrote hb1)
  if (wj == 0) {
    if (tid < 64) {
      const unsigned* fp = &fl[tid & 15];
      while (1) {
        unsigned v = LOAD_SYS((unsigned*)fp);
        if (__all((int)(v >= 201u))) break;
        __builtin_amdgcn_s_sleep(1);
      }
      asm volatile("" ::: "memory");
    }
    __syncthreads();

    const u64* h2 = (const u64*)hb1p;
    int r = tid >> 3, q = tid & 7;
    float sum = 0.f;
#pragma unroll
    for (int c = 0; c < 8; ++c) {
      int k0 = q * 64 + c * 8;
      int kf = k0 >> 5, sub = (k0 >> 3) & 3, m = r >> 4;
      int bq2 = ((kf * 2 + m) * 64 + sub * 16 + (r & 15)) * 2;
      union { u64 u[2]; unsigned short ss[8]; } cv;
      cv.u[0] = LOAD_SYS((u64*)h2 + bq2);
      cv.u[1] = LOAD_SYS((u64*)h2 + bq2 + 1);
#pragma unroll
      for (int e = 0; e < 8; ++e)
        sum = fmaf(bf2f((short)cv.ss[e]), Wfc[k0 + e], sum);
    }
    red[tid] = sum;
    __syncthreads();
    if (q == 0) {
      float o = bfc[0];
#pragma unroll
      for (int j = 0; j < 8; ++j) o += red[r * 8 + j];
      out[gr * 32 + r] = o;
    }
  }
}

extern "C" void kernel_launch(void* const* d_in, const int* in_sizes, int n_in,
                              void* d_out, int out_size, void* d_ws, size_t ws_size,
                              hipStream_t stream)
{
  if (ws_size < WS_NEED) {
    fprintf(stderr, "kernel_launch: ws_size %zu < needed %zu\n", ws_size, WS_NEED);
    return;
  }
  const float* inp = (const float*)d_in[0];
  const float* Wx1 = (const float*)d_in[1];
  const float* Wh1 = (const float*)d_in[2];
  const float* b1  = (const float*)d_in[3];
  const float* Wx2 = (const float*)d_in[4];
  const float* Wh2 = (const float*)d_in[5];
  const float* b2  = (const float*)d_in[6];
  const float* Wfc = (const float*)d_in[7];
  const float* bfc = (const float*)d_in[8];
  unsigned char* ws = (unsigned char*)d_ws;

  hipMemsetAsync(ws, 0, 8192, stream);                        // flags
  pack_w<<<768, 256, 0, stream>>>(Wh1, Wh2, Wx2, ws);
  lstm_main<<<256, 256, 0, stream>>>(inp, Wx1, b1, b2, Wfc, bfc, ws, (float*)d_out);
}